// Round 13
// baseline (83.640 us; speedup 1.0000x reference)
//
#include <hip/hip_runtime.h>
#include <hip/hip_bf16.h>
#include <cstdint>
#include <cstddef>

#define RANK 16

typedef __attribute__((ext_vector_type(8))) short bf16x8;   // 8 bf16 (4 VGPRs)
typedef __attribute__((ext_vector_type(4))) float f32x4;    // MFMA C/D

static __device__ __forceinline__ short f2bf(float f) {
  __hip_bfloat16 h = __float2bfloat16(f);
  return *reinterpret_cast<short*>(&h);
}

// ---------------------------------------------------------------------------
// Kernel 1: mix LoRA factors with per-(batch,split) skill weights.
//   Amt[b][r][k] = bf16( sum_s w[b][q][s] * la[q][s][d][r] ), k = q*512 + d
//   Bm[b][r][o]  = 2 * sum_s w[b][q][s] * lb[q][s][r][dd],   o = q*512 + dd
// (scaling folded into Bm; Bm stays fp32)                     [unchanged]
// ---------------------------------------------------------------------------
__global__ __launch_bounds__(256) void skilled_lora_mix(
    const float* __restrict__ w,       // [8][4][8]
    const float* __restrict__ la,      // [4][8][512][16]
    const float* __restrict__ lb,      // [4][8][16][512]
    __hip_bfloat16* __restrict__ Amt,  // [8][16][2048] bf16
    float* __restrict__ Bm)            // [8][16][2048] fp32, pre-scaled by 2
{
  const int j = blockIdx.x * 256 + threadIdx.x;
  if (j < 65536) {
    const int r0 = (j & 3) * 4;
    const int k  = (j >> 2) & 2047;
    const int b  = j >> 13;
    const int q  = k >> 9;
    const int d  = k & 511;
    const float* wb = w + (b * 4 + q) * 8;
    float4 acc = make_float4(0.f, 0.f, 0.f, 0.f);
#pragma unroll
    for (int s = 0; s < 8; ++s) {
      const float ws = wb[s];
      const float4 v = *reinterpret_cast<const float4*>(
          la + (size_t)(((q * 8 + s) * 512 + d) * 16 + r0));
      acc.x = fmaf(ws, v.x, acc.x);
      acc.y = fmaf(ws, v.y, acc.y);
      acc.z = fmaf(ws, v.z, acc.z);
      acc.w = fmaf(ws, v.w, acc.w);
    }
    Amt[((size_t)(b * 16 + r0 + 0)) * 2048 + k] = __float2bfloat16(acc.x);
    Amt[((size_t)(b * 16 + r0 + 1)) * 2048 + k] = __float2bfloat16(acc.y);
    Amt[((size_t)(b * 16 + r0 + 2)) * 2048 + k] = __float2bfloat16(acc.z);
    Amt[((size_t)(b * 16 + r0 + 3)) * 2048 + k] = __float2bfloat16(acc.w);
  } else {
    const int jj = j - 65536;
    const int o  = (jj & 511) * 4;
    const int r  = (jj >> 9) & 15;
    const int b  = jj >> 13;
    const int q  = o >> 9;
    const int dd = o & 511;
    const float* wb = w + (b * 4 + q) * 8;
    float4 acc = make_float4(0.f, 0.f, 0.f, 0.f);
#pragma unroll
    for (int s = 0; s < 8; ++s) {
      const float ws = wb[s];
      const float4 v = *reinterpret_cast<const float4*>(
          lb + (size_t)(((q * 8 + s) * 16 + r) * 512 + dd));
      acc.x = fmaf(ws, v.x, acc.x);
      acc.y = fmaf(ws, v.y, acc.y);
      acc.z = fmaf(ws, v.z, acc.z);
      acc.w = fmaf(ws, v.w, acc.w);
    }
    acc.x *= 2.f; acc.y *= 2.f; acc.z *= 2.f; acc.w *= 2.f;
    *reinterpret_cast<float4*>(Bm + (size_t)((b * 16 + r) * 2048 + o)) = acc;
  }
}

// ---------------------------------------------------------------------------
// Kernel 2 (phase A, MFMA + SEQUENTIAL block-cooperative stage):
//   tmp_p[ks][b][row][r] partial over a 1024-k half.
//
// ROUND-13: r11/r12 falsified occupancy and per-instr-segment theories; all
// variants share 16-row x 8KB-strided X streams and all sit at ~2.9 TB/s.
// Test: make X reads LANE-LINEAR SEQUENTIAL (the pattern that hits 7 TB/s in
// the fill / m13 copy): wave w loads rows {w, w+4, w+8, w+12} of the tile as
// ONE 1KB-contiguous instruction per row (64 lanes x 16B within a row).
// Chunk = 256 k -> LDS [16][260] (16.6 KB). 2 barriers/chunk; 8 blocks/CU
// hide the stalls. Each wave MFMAs its own 64-k slice of the chunk.
// Fragment math / Amt path / epilogue / decomposition identical to r12
// (validated): grid 2048 = 8b x 128 tiles x 2 ks, (256,8).
// C/D: col=lane&15 (=r), row=(lane>>4)*4+reg.
// ---------------------------------------------------------------------------
#define CK   256                      // chunk k-width
#define XPAD 260                      // row stride in floats

__global__ __launch_bounds__(256, 8) void lora_phase_a(
    const float* __restrict__ X,           // [8][2048][2048]
    const __hip_bfloat16* __restrict__ Amt,// [8][16][2048] bf16
    float* __restrict__ tmp_p)             // [2][8][2048][16] partials
{
  __shared__ float stage[16 * XPAD];       // 16.6 KB

  const int tid  = threadIdx.x;
  const int lane = tid & 63;
  const int wv   = tid >> 6;               // 0..3
  const int b    = blockIdx.x >> 8;        // 8 batches
  const int tile = (blockIdx.x >> 1) & 127;
  const int ks   = blockIdx.x & 1;         // k-split 0..1
  const int row0 = tile * 16;
  const int k0   = ks * 1024;
  const int m    = lane & 15;              // fragment row / r
  const int g    = lane >> 4;              // k-subgroup 0..3

  const float* Xb = X + ((size_t)(b * 2048 + row0)) * 2048 + k0;
  // this wave's k-slice within a chunk: [wv*64, wv*64+64)
  const __hip_bfloat16* Ap = Amt + ((size_t)(b * 16 + m)) * 2048 + k0
                                 + wv * 64 + g * 8;

  f32x4 acc = {0.f, 0.f, 0.f, 0.f};

  for (int c = 0; c < 1024 / CK; ++c) {    // 4 chunks of 256 k
    const int kc = c * CK;
    // ---- stage 16 rows x 256 floats; each instr = 1KB contiguous in a row
#pragma unroll
    for (int i = 0; i < 4; ++i) {
      const int row = i * 4 + wv;          // wave w -> rows w, w+4, w+8, w+12
      const float4 v = *reinterpret_cast<const float4*>(
          Xb + (size_t)row * 2048 + kc + lane * 4);
      *reinterpret_cast<float4*>(&stage[row * XPAD + lane * 4]) = v;
    }
    __syncthreads();                       // stage visible to all waves

    // ---- 2 MFMA steps (K=32 each) on this wave's 64-k slice ----
#pragma unroll
    for (int h = 0; h < 2; ++h) {
      const float4 xlo = *reinterpret_cast<const float4*>(
          &stage[m * XPAD + wv * 64 + h * 32 + g * 8]);
      const float4 xhi = *reinterpret_cast<const float4*>(
          &stage[m * XPAD + wv * 64 + h * 32 + g * 8 + 4]);
      bf16x8 afrag;
      afrag[0] = f2bf(xlo.x); afrag[1] = f2bf(xlo.y);
      afrag[2] = f2bf(xlo.z); afrag[3] = f2bf(xlo.w);
      afrag[4] = f2bf(xhi.x); afrag[5] = f2bf(xhi.y);
      afrag[6] = f2bf(xhi.z); afrag[7] = f2bf(xhi.w);
      const bf16x8 bfrag = *reinterpret_cast<const bf16x8*>(
          Ap + (size_t)(kc + h * 32));
      acc = __builtin_amdgcn_mfma_f32_16x16x32_bf16(afrag, bfrag, acc, 0, 0, 0);
    }
    __syncthreads();                       // reads done before next overwrite
  }

  // ---- epilogue: reuse stage as part[4][16][17] ----
  float* part = stage;
#pragma unroll
  for (int v = 0; v < 4; ++v)
    part[(wv * 16 + g * 4 + v) * 17 + m] = acc[v];
  __syncthreads();

  const int row = tid >> 4;                // 0..15
  const int r   = tid & 15;
  const float s = part[(0 * 16 + row) * 17 + r] + part[(1 * 16 + row) * 17 + r]
                + part[(2 * 16 + row) * 17 + r] + part[(3 * 16 + row) * 17 + r];
  tmp_p[((size_t)((ks * 8 + b) * 2048 + row0 + row)) * RANK + r] = s;
}

// ---------------------------------------------------------------------------
// Kernel 3 (phase B): out[b][row][o] = sum_r (tmp0+tmp1)[b][row][r] * Bm[r][o]
// (unchanged from r11/r12 for attribution)
// ---------------------------------------------------------------------------
__global__ __launch_bounds__(256, 2) void lora_phase_b(
    const float* __restrict__ tmp_p, // [2][8][2048][16] partials
    const float* __restrict__ Bm,    // [8][16][2048] (pre-scaled by 2)
    float* __restrict__ out)         // [8][2048][2048]
{
  const int tid  = threadIdx.x;
  const int b    = blockIdx.x >> 8;          // 8 batches x 256 blocks
  const int oh   = (blockIdx.x >> 7) & 1;    // column half
  const int rt   = blockIdx.x & 127;         // row tile
  const int row0 = rt * 16;
  const int o0   = oh * 1024 + tid * 4;

  const float* Bb = Bm + (size_t)b * (RANK * 2048) + o0;
  float4 B4[RANK];
#pragma unroll
  for (int r = 0; r < RANK; ++r)
    B4[r] = *reinterpret_cast<const float4*>(Bb + (size_t)r * 2048);

  const float* tp0 = tmp_p + ((size_t)(b * 2048 + row0)) * RANK;
  const float* tp1 = tmp_p + ((size_t)((8 + b) * 2048 + row0)) * RANK;
  float* op = out + ((size_t)(b * 2048 + row0)) * 2048 + o0;

#pragma unroll 4
  for (int rr = 0; rr < 16; ++rr) {
    const float4 u0 = *reinterpret_cast<const float4*>(tp0 + rr * RANK);
    const float4 u1 = *reinterpret_cast<const float4*>(tp0 + rr * RANK + 4);
    const float4 u2 = *reinterpret_cast<const float4*>(tp0 + rr * RANK + 8);
    const float4 u3 = *reinterpret_cast<const float4*>(tp0 + rr * RANK + 12);
    const float4 v0 = *reinterpret_cast<const float4*>(tp1 + rr * RANK);
    const float4 v1 = *reinterpret_cast<const float4*>(tp1 + rr * RANK + 4);
    const float4 v2 = *reinterpret_cast<const float4*>(tp1 + rr * RANK + 8);
    const float4 v3 = *reinterpret_cast<const float4*>(tp1 + rr * RANK + 12);
    const float4 t0 = make_float4(u0.x + v0.x, u0.y + v0.y, u0.z + v0.z, u0.w + v0.w);
    const float4 t1 = make_float4(u1.x + v1.x, u1.y + v1.y, u1.z + v1.z, u1.w + v1.w);
    const float4 t2 = make_float4(u2.x + v2.x, u2.y + v2.y, u2.z + v2.z, u2.w + v2.w);
    const float4 t3 = make_float4(u3.x + v3.x, u3.y + v3.y, u3.z + v3.z, u3.w + v3.w);
    float4 a = make_float4(0.f, 0.f, 0.f, 0.f);
    a.x = fmaf(t0.x, B4[0].x, a.x);  a.y = fmaf(t0.x, B4[0].y, a.y);
    a.z = fmaf(t0.x, B4[0].z, a.z);  a.w = fmaf(t0.x, B4[0].w, a.w);
    a.x = fmaf(t0.y, B4[1].x, a.x);  a.y = fmaf(t0.y, B4[1].y, a.y);
    a.z = fmaf(t0.y, B4[1].z, a.z);  a.w = fmaf(t0.y, B4[1].w, a.w);
    a.x = fmaf(t0.z, B4[2].x, a.x);  a.y = fmaf(t0.z, B4[2].y, a.y);
    a.z = fmaf(t0.z, B4[2].z, a.z);  a.w = fmaf(t0.z, B4[2].w, a.w);
    a.x = fmaf(t0.w, B4[3].x, a.x);  a.y = fmaf(t0.w, B4[3].y, a.y);
    a.z = fmaf(t0.w, B4[3].z, a.z);  a.w = fmaf(t0.w, B4[3].w, a.w);
    a.x = fmaf(t1.x, B4[4].x, a.x);  a.y = fmaf(t1.x, B4[4].y, a.y);
    a.z = fmaf(t1.x, B4[4].z, a.z);  a.w = fmaf(t1.x, B4[4].w, a.w);
    a.x = fmaf(t1.y, B4[5].x, a.x);  a.y = fmaf(t1.y, B4[5].y, a.y);
    a.z = fmaf(t1.y, B4[5].z, a.z);  a.w = fmaf(t1.y, B4[5].w, a.w);
    a.x = fmaf(t1.z, B4[6].x, a.x);  a.y = fmaf(t1.z, B4[6].y, a.y);
    a.z = fmaf(t1.z, B4[6].z, a.z);  a.w = fmaf(t1.z, B4[6].w, a.w);
    a.x = fmaf(t1.w, B4[7].x, a.x);  a.y = fmaf(t1.w, B4[7].y, a.y);
    a.z = fmaf(t1.w, B4[7].z, a.z);  a.w = fmaf(t1.w, B4[7].w, a.w);
    a.x = fmaf(t2.x, B4[8].x, a.x);  a.y = fmaf(t2.x, B4[8].y, a.y);
    a.z = fmaf(t2.x, B4[8].z, a.z);  a.w = fmaf(t2.x, B4[8].w, a.w);
    a.x = fmaf(t2.y, B4[9].x, a.x);  a.y = fmaf(t2.y, B4[9].y, a.y);
    a.z = fmaf(t2.y, B4[9].z, a.z);  a.w = fmaf(t2.y, B4[9].w, a.w);
    a.x = fmaf(t2.z, B4[10].x, a.x); a.y = fmaf(t2.z, B4[10].y, a.y);
    a.z = fmaf(t2.z, B4[10].z, a.z); a.w = fmaf(t2.z, B4[10].w, a.w);
    a.x = fmaf(t2.w, B4[11].x, a.x); a.y = fmaf(t2.w, B4[11].y, a.y);
    a.z = fmaf(t2.w, B4[11].z, a.z); a.w = fmaf(t2.w, B4[11].w, a.w);
    a.x = fmaf(t3.x, B4[12].x, a.x); a.y = fmaf(t3.x, B4[12].y, a.y);
    a.z = fmaf(t3.x, B4[12].z, a.z); a.w = fmaf(t3.x, B4[12].w, a.w);
    a.x = fmaf(t3.y, B4[13].x, a.x); a.y = fmaf(t3.y, B4[13].y, a.y);
    a.z = fmaf(t3.y, B4[13].z, a.z); a.w = fmaf(t3.y, B4[13].w, a.w);
    a.x = fmaf(t3.z, B4[14].x, a.x); a.y = fmaf(t3.z, B4[14].y, a.y);
    a.z = fmaf(t3.z, B4[14].z, a.z); a.w = fmaf(t3.z, B4[14].w, a.w);
    a.x = fmaf(t3.w, B4[15].x, a.x); a.y = fmaf(t3.w, B4[15].y, a.y);
    a.z = fmaf(t3.w, B4[15].z, a.z); a.w = fmaf(t3.w, B4[15].w, a.w);
    *reinterpret_cast<float4*>(op + (size_t)rr * 2048) = a;
  }
}

// ---------------------------------------------------------------------------
extern "C" void kernel_launch(void* const* d_in, const int* in_sizes, int n_in,
                              void* d_out, int out_size, void* d_ws, size_t ws_size,
                              hipStream_t stream) {
  const float* input = (const float*)d_in[0];   // [8][2048][2048]
  const float* w     = (const float*)d_in[1];   // [8][4][8]
  const float* la    = (const float*)d_in[2];   // [4][8][512][16]
  const float* lb    = (const float*)d_in[3];   // [4][8][16][512]
  float* outp = (float*)d_out;

  __hip_bfloat16* Amt = (__hip_bfloat16*)d_ws;                      // 512 KB
  float* Bm    = (float*)((char*)d_ws + (size_t)8 * 16 * 2048 * 2); // 1 MB
  float* tmp_p = Bm + 8 * RANK * 2048;                              // 2 MB

  skilled_lora_mix<<<512, 256, 0, stream>>>(w, la, lb, Amt, Bm);
  lora_phase_a<<<2048, 256, 0, stream>>>(input, Amt, tmp_p);
  lora_phase_b<<<2048, 256, 0, stream>>>(tmp_p, Bm, outp);
}